// Round 19
// baseline (357.504 us; speedup 1.0000x reference)
//
#include <hip/hip_runtime.h>

typedef __bf16 bf16x8 __attribute__((ext_vector_type(8)));
typedef __bf16 bf16x4 __attribute__((ext_vector_type(4)));
typedef float  f32x16 __attribute__((ext_vector_type(16)));

#define DDEC  176
#define DSP   54
#define HID   256
#define RPW   32             // rows per wave (32x32 MFMA N-dim)
#define WPB   8              // waves per block
#define BM    (RPW * WPB)    // 256 rows per block
#define NTHR  (WPB * 64)     // 512 threads
#define CSZ   8192           // elems per 32-col weight chunk (16KB)
#define W1_OFF 65536
#define W2_OFF 131072
#define MLP_WS 139264

struct Biases { const float* b1[3]; const float* b2[3]; };

// ---- prep: pad/transpose weights to bf16 [col][256 k] per layer
// W0p[256][256] (k<222 = w0[k][n], k==222 = b0[n], else 0), W1p[256][256], W2p[32][256]
__global__ __launch_bounds__(256) void prep_weights(
    const float* __restrict__ w0a, const float* __restrict__ w1a, const float* __restrict__ w2a,
    const float* __restrict__ w0b, const float* __restrict__ w1b, const float* __restrict__ w2b,
    const float* __restrict__ w0c, const float* __restrict__ w1c, const float* __restrict__ w2c,
    const float* __restrict__ b0a, const float* __restrict__ b0b, const float* __restrict__ b0c,
    __bf16* __restrict__ ws)
{
  int idx = blockIdx.x * 256 + threadIdx.x;
  if (idx >= 3 * MLP_WS) return;
  int m = idx / MLP_WS;
  int r = idx - m * MLP_WS;
  const float* w0 = (m == 0) ? w0a : (m == 1) ? w0b : w0c;
  const float* w1 = (m == 0) ? w1a : (m == 1) ? w1b : w1c;
  const float* w2 = (m == 0) ? w2a : (m == 1) ? w2b : w2c;
  const float* b0 = (m == 0) ? b0a : (m == 1) ? b0b : b0c;
  float v;
  if (r < W1_OFF) {
    int n = r >> 8, k = r & 255;
    v = (k < 222) ? w0[k * HID + n] : (k == 222 ? b0[n] : 0.0f);
  } else if (r < W2_OFF) {
    int rr = r - W1_OFF;
    int n = rr >> 8, k = rr & 255;
    v = w1[k * HID + n];
  } else {
    int rr = r - W2_OFF;
    int n = rr >> 8, k = rr & 255;
    int od = (m == 0) ? 8 : 24;
    v = (n < od) ? w2[k * od + n] : 0.0f;
  }
  ws[idx] = (__bf16)v;
}

__device__ __forceinline__ float lrelu(float v) { return v > 0.f ? v : 0.01f * v; }

__device__ __forceinline__ void gload16(const void* g, void* l) {
  __builtin_amdgcn_global_load_lds(
      (const __attribute__((address_space(1))) void*)g,
      (__attribute__((address_space(3))) void*)l, 16, 0, 0);
}

// stage one 32-col chunk (16KB) with 512 threads (2 rounds x 8KB = 2 vmem/thread);
// source pre-swizzled so LDS byte a holds W[col=a>>9][k_byte=(a&511)^((col&31)<<4)]
__device__ __forceinline__ void stage(const __bf16* __restrict__ wsrc, __bf16* buf, int tid) {
  #pragma unroll
  for (int r = 0; r < 2; ++r) {
    const int a  = (r * NTHR + tid) * 16;
    const int lc = a >> 9;
    const int un = (a & 511) ^ ((lc & 31) << 4);
    gload16(wsrc + lc * 256 + (un >> 1), (char*)buf + r * (NTHR * 16) + (tid >> 6) * 1024);
  }
}

// 32-col chunk: acc += W[r32][k] x B[k]  (swizzled ds_read_b128 A-frags)
template<int NKK>
__device__ __forceinline__ void gemm1(const __bf16* buf, const bf16x8* bfr,
                                      f32x16& acc, int r32, int h) {
  const int sw = r32 << 4;
  const char* abase = (const char*)buf + (r32 << 9);
  #pragma unroll
  for (int kk = 0; kk < NKK; ++kk) {
    const int inner = ((kk << 5) + (h << 4)) ^ sw;
    bf16x8 a0 = *(const bf16x8*)(abase + inner);
    acc = __builtin_amdgcn_mfma_f32_32x32x16_bf16(a0, bfr[kk], acc, 0, 0, 0);
  }
}

// L1 variant: per-wave rotated k-order (kk0 = 2*wid) to de-convoy the 8 waves'
// simultaneous bursts on the LDS read queue. NKK must be a power of 2.
template<int NKK>
__device__ __forceinline__ void gemm1rot(const __bf16* buf, const bf16x8* bfr,
                                         f32x16& acc, int r32, int h, int kk0) {
  const int sw = r32 << 4;
  const char* abase = (const char*)buf + (r32 << 9);
  #pragma unroll
  for (int kk = 0; kk < NKK; ++kk) {
    const int k2 = (kk + kk0) & (NKK - 1);
    const int inner = ((k2 << 5) + (h << 4)) ^ sw;
    bf16x8 a0 = *(const bf16x8*)(abase + inner);
    acc = __builtin_amdgcn_mfma_f32_32x32x16_bf16(a0, bfr[k2], acc, 0, 0, 0);
  }
}

__device__ __forceinline__ bf16x4 shfl32(bf16x4 x) {
  union { bf16x4 v; unsigned long long u; } t;
  t.v = x;
  t.u = __shfl_xor(t.u, 32, 64);
  return t.v;
}
__device__ __forceinline__ bf16x8 cat44(bf16x4 lo, bf16x4 hi) {
  return (bf16x8){lo[0], lo[1], lo[2], lo[3], hi[0], hi[1], hi[2], hi[3]};
}

struct Frag2 { bf16x8 f0, f1; };

// One 32-col D block -> 2 next-layer B-frags (k = 32c..+16, 32c+16..+32).
// D layout (verified): n = lane&31, m = (reg&3) + 8*(reg>>2) + 4*h. Lane-half h owns
// quads {2t+h}; one shfl_xor(32) per 2 quads completes each frag.
// Bias (if any) comes PRELOADED in bv[4] (issued before the gemm so the global
// load latency hides under the MFMAs instead of gating the transition).
template<bool BIAS, bool LR>
__device__ __forceinline__ Frag2 d2frags(const f32x16 acc, const float4* bv, int h) {
  bf16x4 pk[4];
  #pragma unroll
  for (int t = 0; t < 4; ++t) {
    float bx = 0.f, by = 0.f, bz = 0.f, bw = 0.f;
    if (BIAS) { bx = bv[t].x; by = bv[t].y; bz = bv[t].z; bw = bv[t].w; }
    float v0 = acc[4 * t] + bx, v1 = acc[4 * t + 1] + by;
    float v2 = acc[4 * t + 2] + bz, v3 = acc[4 * t + 3] + bw;
    if (LR) { v0 = lrelu(v0); v1 = lrelu(v1); v2 = lrelu(v2); v3 = lrelu(v3); }
    pk[t] = (bf16x4){(__bf16)v0, (__bf16)v1, (__bf16)v2, (__bf16)v3};
  }
  bf16x4 r1 = shfl32(h ? pk[0] : pk[1]);
  bf16x4 r2 = shfl32(h ? pk[2] : pk[3]);
  Frag2 out;
  out.f0 = h ? cat44(r1, pk[1]) : cat44(pk[0], r1);
  out.f1 = h ? cat44(r2, pk[3]) : cat44(pk[2], r2);
  return out;
}

__device__ __forceinline__ bf16x8 packf44(float4 a, float4 b) {
  return (bf16x8){(__bf16)a.x, (__bf16)a.y, (__bf16)a.z, (__bf16)a.w,
                  (__bf16)b.x, (__bf16)b.y, (__bf16)b.z, (__bf16)b.w};
}
__device__ __forceinline__ bf16x8 packf2222(float2 a, float2 b, float2 c, float2 d) {
  return (bf16x8){(__bf16)a.x, (__bf16)a.y, (__bf16)b.x, (__bf16)b.y,
                  (__bf16)c.x, (__bf16)c.y, (__bf16)d.x, (__bf16)d.y};
}

__global__ __launch_bounds__(NTHR, 2) void trunk_fused(
    const float* __restrict__ sparse, const float* __restrict__ dec,
    const __bf16* __restrict__ ws, float* __restrict__ out, Biases bp)
{
  __shared__ __align__(16) __bf16 lds[2 * CSZ];  // 32KB: 2 x 16KB chunk buffers
  __bf16* const buf0 = lds;
  __bf16* const buf1 = lds + CSZ;

  const int tid  = threadIdx.x;
  const int lane = tid & 63;
  const int wid  = tid >> 6;
  const int r32  = lane & 31;     // x-row within wave / W-col within 32-chunk
  const int h    = lane >> 5;     // k sub-half
  const long grow = (long)blockIdx.x * BM + wid * RPW + r32;

  // issue first stage (MLP0 W0 chunk 0) before the gather, hide latency
  stage(ws, buf0, tid);

  // ---- gather x B-frags: xb[kf] = x[row=r32][k = 16kf + 8h .. +8]; chunk cc = 2kf+h
  // node order [0,3,6,9,12,13,14,15,16,17,18,19,20,21] + parent chain 21..0
  bf16x8 xb[14];
  {
    constexpr int ND[21] = {0,3,6,9,12,13,14,15,16,17,18,19,20,21,19,17,14,9,6,3,0};
    const float* drow = dec + grow * DDEC;
    const float* srow = sparse + grow * DSP;
    #pragma unroll
    for (int kf = 0; kf < 14; ++kf) {
      if (kf <= 9) {
        const int off = (h ? ND[2 * kf + 1] : ND[2 * kf]) * 8;
        const float4* p = (const float4*)(drow + off);
        xb[kf] = packf44(p[0], p[1]);
      } else if (kf == 10) {
        if (h == 0) {
          const float4* p = (const float4*)(drow + ND[20] * 8);
          xb[kf] = packf44(p[0], p[1]);
        } else {
          const float2* q = (const float2*)(srow + 0);
          xb[kf] = packf2222(q[0], q[1], q[2], q[3]);
        }
      } else if (kf <= 12) {
        const float2* q = (const float2*)(srow + (2 * kf + h - 21) * 8);
        xb[kf] = packf2222(q[0], q[1], q[2], q[3]);
      } else {
        if (h == 0) {
          const float2* q = (const float2*)(srow + 40);
          xb[kf] = packf2222(q[0], q[1], q[2], q[3]);
        } else {
          const float2* q = (const float2*)(srow + 48);
          xb[kf] = packf2222(q[0], q[1], q[2], make_float2(1.0f, 0.0f));  // k222 = b0 hook
        }
      }
    }
  }
  __syncthreads();
  int pb = 0;

  for (int m = 0; m < 3; ++m) {
    const __bf16* W0 = ws + m * MLP_WS;
    const __bf16* W1 = W0 + W1_OFF;
    const __bf16* W2 = W0 + W2_OFF;
    const float* b1 = bp.b1[m];
    const float* b2 = bp.b2[m];

    bf16x8 hb1[16];
    f32x16 a2 = {};   // layer-2 accumulator, filled across the 8 layer-1 chunks

    // ---- layer 0: 8 chunks of 32 h1-cols, K=224 (14 k-steps), bias folded at k=222
    #pragma unroll
    for (int c = 0; c < 8; ++c) {
      __bf16* cur = pb ? buf1 : buf0;
      __bf16* nxt = pb ? buf0 : buf1;
      stage(c < 7 ? W0 + (c + 1) * CSZ : W1, nxt, tid);
      f32x16 acc = {};
      gemm1<14>(cur, xb, acc, r32, h);
      Frag2 t = d2frags<false, true>(acc, nullptr, h);
      hb1[2 * c]     = t.f0;
      hb1[2 * c + 1] = t.f1;
      __syncthreads();
      pb ^= 1;
    }

    // ---- layer 1 (8 chunks, K=256) with layer 2 folded in per chunk.
    // W2 A-frags and b1 bias float4s are ISSUED BEFORE the gemm so their
    // global-load latency hides under the 16 MFMAs (they gate only d2frags/a2).
    #pragma unroll
    for (int c = 0; c < 8; ++c) {
      __bf16* cur = pb ? buf1 : buf0;
      __bf16* nxt = pb ? buf0 : buf1;
      const __bf16* w2f = W2 + r32 * 256 + h * 8 + 32 * c;
      bf16x8 wa0 = *(const bf16x8*)(w2f + 0);
      bf16x8 wa1 = *(const bf16x8*)(w2f + 16);
      float4 bv[4];
      #pragma unroll
      for (int t = 0; t < 4; ++t) bv[t] = *(const float4*)(b1 + 32 * c + 8 * t + 4 * h);
      if (c < 7)      stage(W1 + (c + 1) * CSZ, nxt, tid);
      else if (m < 2) stage(ws + (m + 1) * MLP_WS, nxt, tid);
      f32x16 acc = {};
      gemm1rot<16>(cur, hb1, acc, r32, h, 2 * wid);
      Frag2 t = d2frags<true, true>(acc, bv, h);
      a2 = __builtin_amdgcn_mfma_f32_32x32x16_bf16(wa0, t.f0, a2, 0, 0, 0);
      a2 = __builtin_amdgcn_mfma_f32_32x32x16_bf16(wa1, t.f1, a2, 0, 0, 0);
      __syncthreads();
      pb ^= 1;
    }

    // ---- epilogue: a2 = out^T frag (lane r32 = its own x-row; quads 2t+h -> cols 8t+4h..+3)
    if (m == 2) {
      #pragma unroll
      for (int t = 0; t < 3; ++t) {
        const int c0 = 8 * t + 4 * h;
        float4 bvv = *(const float4*)(b2 + c0);
        float4 o;
        o.x = a2[4 * t]     + bvv.x;
        o.y = a2[4 * t + 1] + bvv.y;
        o.z = a2[4 * t + 2] + bvv.z;
        o.w = a2[4 * t + 3] + bvv.w;
        *(float4*)(out + grow * 24 + c0) = o;
      }
    } else {
      bf16x4 pk[3];
      #pragma unroll
      for (int t = 0; t < 3; ++t) {
        const int c0 = 8 * t + 4 * h;
        float4 bvv = *(const float4*)(b2 + c0);
        pk[t] = (bf16x4){(__bf16)(a2[4 * t] + bvv.x),     (__bf16)(a2[4 * t + 1] + bvv.y),
                         (__bf16)(a2[4 * t + 2] + bvv.z), (__bf16)(a2[4 * t + 3] + bvv.w)};
      }
      if (m == 0) {
        // res1 = joint 9 (cols 0-7) -> chunks 3 (xb[1],h1) and 17 (xb[8],h1)
        bf16x4 r = shfl32(pk[0]);
        if (h) { bf16x8 f = cat44(r, pk[0]); xb[1] = f; xb[8] = f; }
      } else {
        // res2: joint6 (0-7)->chunks 2,18 (h0); joint9 (8-15)->3,17 (h1); joint12 (16-23)->4 (h0)
        bf16x4 r1 = shfl32(h ? pk[0] : pk[1]);
        bf16x4 r2 = shfl32(pk[2]);
        if (h) {
          bf16x8 fJ9 = cat44(r1, pk[1]);  xb[1] = fJ9;  xb[8] = fJ9;
        } else {
          bf16x8 fJ6  = cat44(pk[0], r1); xb[1] = fJ6;  xb[9] = fJ6;
          bf16x8 fJ12 = cat44(pk[2], r2); xb[2] = fJ12;
        }
      }
    }
  }
}

extern "C" void kernel_launch(void* const* d_in, const int* in_sizes, int n_in,
                              void* d_out, int out_size, void* d_ws, size_t ws_size,
                              hipStream_t stream)
{
  const float* sparse = (const float*)d_in[0];
  const float* dec    = (const float*)d_in[1];
  Biases bp;
  const float* w0[3]; const float* w1[3]; const float* w2[3]; const float* b0[3];
  for (int m = 0; m < 3; ++m) {
    w0[m]    = (const float*)d_in[2 + m * 6 + 0];
    b0[m]    = (const float*)d_in[2 + m * 6 + 1];
    w1[m]    = (const float*)d_in[2 + m * 6 + 2];
    bp.b1[m] = (const float*)d_in[2 + m * 6 + 3];
    w2[m]    = (const float*)d_in[2 + m * 6 + 4];
    bp.b2[m] = (const float*)d_in[2 + m * 6 + 5];
  }
  __bf16* ws = (__bf16*)d_ws;
  const int nrows = in_sizes[0] / DSP;   // 131072 = 512 * 256

  const int prep_total = 3 * MLP_WS;
  prep_weights<<<(prep_total + 255) / 256, 256, 0, stream>>>(
      w0[0], w1[0], w2[0], w0[1], w1[1], w2[1], w0[2], w1[2], w2[2],
      b0[0], b0[1], b0[2], ws);

  const int nblocks = nrows / BM;
  trunk_fused<<<nblocks, NTHR, 0, stream>>>(sparse, dec, ws, (float*)d_out, bp);
}

// Round 20
// 132.415 us; speedup vs baseline: 2.6999x; 2.6999x over previous
//
#include <hip/hip_runtime.h>

typedef __bf16 bf16x8 __attribute__((ext_vector_type(8)));
typedef __bf16 bf16x4 __attribute__((ext_vector_type(4)));
typedef float  f32x16 __attribute__((ext_vector_type(16)));

#define DDEC  176
#define DSP   54
#define HID   256
#define RPW   32             // rows per wave (32x32 MFMA N-dim)
#define WPB   8              // waves per block
#define BM    (RPW * WPB)    // 256 rows per block
#define NTHR  (WPB * 64)     // 512 threads
#define CSZ   8192           // elems per 32-col weight chunk (16KB)
#define W1_OFF 65536
#define W2_OFF 131072
#define MLP_WS 139264

struct Biases { const float* b1[3]; const float* b2[3]; };

// ---- prep: pad/transpose weights to bf16 [col][256 k] per layer
// W0p[256][256] (k<222 = w0[k][n], k==222 = b0[n], else 0), W1p[256][256], W2p[32][256]
__global__ __launch_bounds__(256) void prep_weights(
    const float* __restrict__ w0a, const float* __restrict__ w1a, const float* __restrict__ w2a,
    const float* __restrict__ w0b, const float* __restrict__ w1b, const float* __restrict__ w2b,
    const float* __restrict__ w0c, const float* __restrict__ w1c, const float* __restrict__ w2c,
    const float* __restrict__ b0a, const float* __restrict__ b0b, const float* __restrict__ b0c,
    __bf16* __restrict__ ws)
{
  int idx = blockIdx.x * 256 + threadIdx.x;
  if (idx >= 3 * MLP_WS) return;
  int m = idx / MLP_WS;
  int r = idx - m * MLP_WS;
  const float* w0 = (m == 0) ? w0a : (m == 1) ? w0b : w0c;
  const float* w1 = (m == 0) ? w1a : (m == 1) ? w1b : w1c;
  const float* w2 = (m == 0) ? w2a : (m == 1) ? w2b : w2c;
  const float* b0 = (m == 0) ? b0a : (m == 1) ? b0b : b0c;
  float v;
  if (r < W1_OFF) {
    int n = r >> 8, k = r & 255;
    v = (k < 222) ? w0[k * HID + n] : (k == 222 ? b0[n] : 0.0f);
  } else if (r < W2_OFF) {
    int rr = r - W1_OFF;
    int n = rr >> 8, k = rr & 255;
    v = w1[k * HID + n];
  } else {
    int rr = r - W2_OFF;
    int n = rr >> 8, k = rr & 255;
    int od = (m == 0) ? 8 : 24;
    v = (n < od) ? w2[k * od + n] : 0.0f;
  }
  ws[idx] = (__bf16)v;
}

__device__ __forceinline__ float lrelu(float v) { return v > 0.f ? v : 0.01f * v; }

__device__ __forceinline__ void gload16(const void* g, void* l) {
  __builtin_amdgcn_global_load_lds(
      (const __attribute__((address_space(1))) void*)g,
      (__attribute__((address_space(3))) void*)l, 16, 0, 0);
}

// stage one 32-col chunk (16KB) with 512 threads (2 rounds x 8KB); source
// pre-swizzled so LDS byte a holds W[col = a>>9][k_byte = (a&511) ^ ((col&31)<<4)]
__device__ __forceinline__ void stage(const __bf16* __restrict__ wsrc, __bf16* buf, int tid) {
  #pragma unroll
  for (int r = 0; r < 2; ++r) {
    const int a  = (r * NTHR + tid) * 16;
    const int lc = a >> 9;
    const int un = (a & 511) ^ ((lc & 31) << 4);
    gload16(wsrc + lc * 256 + (un >> 1), (char*)buf + r * (NTHR * 16) + (tid >> 6) * 1024);
  }
}

// 32-col chunk: acc += W[r32][k] x B[k]  (swizzled ds_read_b128 A-frags)
template<int NKK>
__device__ __forceinline__ void gemm1(const __bf16* buf, const bf16x8* bfr,
                                      f32x16& acc, int r32, int h) {
  const int sw = r32 << 4;
  const char* abase = (const char*)buf + (r32 << 9);
  #pragma unroll
  for (int kk = 0; kk < NKK; ++kk) {
    const int inner = ((kk << 5) + (h << 4)) ^ sw;
    bf16x8 a0 = *(const bf16x8*)(abase + inner);
    acc = __builtin_amdgcn_mfma_f32_32x32x16_bf16(a0, bfr[kk], acc, 0, 0, 0);
  }
}

__device__ __forceinline__ bf16x4 shfl32(bf16x4 x) {
  union { bf16x4 v; unsigned long long u; } t;
  t.v = x;
  t.u = __shfl_xor(t.u, 32, 64);
  return t.v;
}
__device__ __forceinline__ bf16x8 cat44(bf16x4 lo, bf16x4 hi) {
  return (bf16x8){lo[0], lo[1], lo[2], lo[3], hi[0], hi[1], hi[2], hi[3]};
}

struct Frag2 { bf16x8 f0, f1; };

// One 32-col D block -> 2 next-layer B-frags (k = 32c..+16, 32c+16..+32).
// D layout (verified): n = lane&31, m = (reg&3) + 8*(reg>>2) + 4*h. Lane-half h owns
// quads {2t+h}; one shfl_xor(32) per 2 quads completes each frag.
template<bool BIAS, bool LR>
__device__ __forceinline__ Frag2 d2frags(const f32x16 acc, const float* bias, int h) {
  bf16x4 pk[4];
  #pragma unroll
  for (int t = 0; t < 4; ++t) {
    float bx = 0.f, by = 0.f, bz = 0.f, bw = 0.f;
    if (BIAS) {
      float4 bv = *(const float4*)(bias + 8 * t + 4 * h);
      bx = bv.x; by = bv.y; bz = bv.z; bw = bv.w;
    }
    float v0 = acc[4 * t] + bx, v1 = acc[4 * t + 1] + by;
    float v2 = acc[4 * t + 2] + bz, v3 = acc[4 * t + 3] + bw;
    if (LR) { v0 = lrelu(v0); v1 = lrelu(v1); v2 = lrelu(v2); v3 = lrelu(v3); }
    pk[t] = (bf16x4){(__bf16)v0, (__bf16)v1, (__bf16)v2, (__bf16)v3};
  }
  bf16x4 r1 = shfl32(h ? pk[0] : pk[1]);
  bf16x4 r2 = shfl32(h ? pk[2] : pk[3]);
  Frag2 out;
  out.f0 = h ? cat44(r1, pk[1]) : cat44(pk[0], r1);
  out.f1 = h ? cat44(r2, pk[3]) : cat44(pk[2], r2);
  return out;
}

__device__ __forceinline__ bf16x8 packf44(float4 a, float4 b) {
  return (bf16x8){(__bf16)a.x, (__bf16)a.y, (__bf16)a.z, (__bf16)a.w,
                  (__bf16)b.x, (__bf16)b.y, (__bf16)b.z, (__bf16)b.w};
}
__device__ __forceinline__ bf16x8 packf2222(float2 a, float2 b, float2 c, float2 d) {
  return (bf16x8){(__bf16)a.x, (__bf16)a.y, (__bf16)b.x, (__bf16)b.y,
                  (__bf16)c.x, (__bf16)c.y, (__bf16)d.x, (__bf16)d.y};
}

__global__ __launch_bounds__(NTHR, 2) void trunk_fused(
    const float* __restrict__ sparse, const float* __restrict__ dec,
    const __bf16* __restrict__ ws, float* __restrict__ out, Biases bp)
{
  __shared__ __align__(16) __bf16 lds[2 * CSZ];  // 32KB: 2 x 16KB chunk buffers
  __bf16* const buf0 = lds;
  __bf16* const buf1 = lds + CSZ;

  const int tid  = threadIdx.x;
  const int lane = tid & 63;
  const int wid  = tid >> 6;
  const int r32  = lane & 31;     // x-row within wave / W-col within 32-chunk
  const int h    = lane >> 5;     // k sub-half
  const long grow = (long)blockIdx.x * BM + wid * RPW + r32;

  // issue first stage (MLP0 W0 chunk 0) before the gather, hide latency
  stage(ws, buf0, tid);

  // ---- gather x B-frags: xb[kf] = x[row=r32][k = 16kf + 8h .. +8]; chunk cc = 2kf+h
  // node order [0,3,6,9,12,13,14,15,16,17,18,19,20,21] + parent chain 21..0
  bf16x8 xb[14];
  {
    constexpr int ND[21] = {0,3,6,9,12,13,14,15,16,17,18,19,20,21,19,17,14,9,6,3,0};
    const float* drow = dec + grow * DDEC;
    const float* srow = sparse + grow * DSP;
    #pragma unroll
    for (int kf = 0; kf < 14; ++kf) {
      if (kf <= 9) {
        const int off = (h ? ND[2 * kf + 1] : ND[2 * kf]) * 8;
        const float4* p = (const float4*)(drow + off);
        xb[kf] = packf44(p[0], p[1]);
      } else if (kf == 10) {
        if (h == 0) {
          const float4* p = (const float4*)(drow + ND[20] * 8);
          xb[kf] = packf44(p[0], p[1]);
        } else {
          const float2* q = (const float2*)(srow + 0);
          xb[kf] = packf2222(q[0], q[1], q[2], q[3]);
        }
      } else if (kf <= 12) {
        const float2* q = (const float2*)(srow + (2 * kf + h - 21) * 8);
        xb[kf] = packf2222(q[0], q[1], q[2], q[3]);
      } else {
        if (h == 0) {
          const float2* q = (const float2*)(srow + 40);
          xb[kf] = packf2222(q[0], q[1], q[2], q[3]);
        } else {
          const float2* q = (const float2*)(srow + 48);
          xb[kf] = packf2222(q[0], q[1], q[2], make_float2(1.0f, 0.0f));  // k222 = b0 hook
        }
      }
    }
  }
  __syncthreads();
  int pb = 0;

  for (int m = 0; m < 3; ++m) {
    const __bf16* W0 = ws + m * MLP_WS;
    const __bf16* W1 = W0 + W1_OFF;
    const __bf16* W2 = W0 + W2_OFF;
    const float* b1 = bp.b1[m];
    const float* b2 = bp.b2[m];

    bf16x8 hb1[16];
    f32x16 a2 = {};   // layer-2 accumulator, filled across the 8 layer-1 chunks

    // ---- layer 0: 8 chunks of 32 h1-cols, K=224 (14 k-steps), bias folded at k=222
    #pragma unroll
    for (int c = 0; c < 8; ++c) {
      __bf16* cur = pb ? buf1 : buf0;
      __bf16* nxt = pb ? buf0 : buf1;
      stage(c < 7 ? W0 + (c + 1) * CSZ : W1, nxt, tid);
      f32x16 acc = {};
      gemm1<14>(cur, xb, acc, r32, h);
      Frag2 t = d2frags<false, true>(acc, nullptr, h);
      hb1[2 * c]     = t.f0;
      hb1[2 * c + 1] = t.f1;
      __syncthreads();
      pb ^= 1;
    }

    // ---- layer 1 (8 chunks, K=256) with layer 2 folded in per chunk.
    // Layer-2 A-frags (W2, 16KB, L2-hot) read straight from global, issued
    // before gemm1 so the latency hides under the 16 MFMAs.
    #pragma unroll
    for (int c = 0; c < 8; ++c) {
      __bf16* cur = pb ? buf1 : buf0;
      __bf16* nxt = pb ? buf0 : buf1;
      const __bf16* w2f = W2 + r32 * 256 + h * 8 + 32 * c;
      bf16x8 wa0 = *(const bf16x8*)(w2f + 0);
      bf16x8 wa1 = *(const bf16x8*)(w2f + 16);
      if (c < 7)      stage(W1 + (c + 1) * CSZ, nxt, tid);
      else if (m < 2) stage(ws + (m + 1) * MLP_WS, nxt, tid);
      f32x16 acc = {};
      gemm1<16>(cur, hb1, acc, r32, h);
      Frag2 t = d2frags<true, true>(acc, b1 + 32 * c, h);
      a2 = __builtin_amdgcn_mfma_f32_32x32x16_bf16(wa0, t.f0, a2, 0, 0, 0);
      a2 = __builtin_amdgcn_mfma_f32_32x32x16_bf16(wa1, t.f1, a2, 0, 0, 0);
      __syncthreads();
      pb ^= 1;
    }

    // ---- epilogue: a2 = out^T frag (lane r32 = its own x-row; quads 2t+h -> cols 8t+4h..+3)
    if (m == 2) {
      #pragma unroll
      for (int t = 0; t < 3; ++t) {
        const int c0 = 8 * t + 4 * h;
        float4 bv = *(const float4*)(b2 + c0);
        float4 o;
        o.x = a2[4 * t]     + bv.x;
        o.y = a2[4 * t + 1] + bv.y;
        o.z = a2[4 * t + 2] + bv.z;
        o.w = a2[4 * t + 3] + bv.w;
        *(float4*)(out + grow * 24 + c0) = o;
      }
    } else {
      bf16x4 pk[3];
      #pragma unroll
      for (int t = 0; t < 3; ++t) {
        const int c0 = 8 * t + 4 * h;
        float4 bv = *(const float4*)(b2 + c0);
        pk[t] = (bf16x4){(__bf16)(a2[4 * t] + bv.x),     (__bf16)(a2[4 * t + 1] + bv.y),
                         (__bf16)(a2[4 * t + 2] + bv.z), (__bf16)(a2[4 * t + 3] + bv.w)};
      }
      if (m == 0) {
        // res1 = joint 9 (cols 0-7) -> chunks 3 (xb[1],h1) and 17 (xb[8],h1)
        bf16x4 r = shfl32(pk[0]);
        if (h) { bf16x8 f = cat44(r, pk[0]); xb[1] = f; xb[8] = f; }
      } else {
        // res2: joint6 (0-7)->chunks 2,18 (h0); joint9 (8-15)->3,17 (h1); joint12 (16-23)->4 (h0)
        bf16x4 r1 = shfl32(h ? pk[0] : pk[1]);
        bf16x4 r2 = shfl32(pk[2]);
        if (h) {
          bf16x8 fJ9 = cat44(r1, pk[1]);  xb[1] = fJ9;  xb[8] = fJ9;
        } else {
          bf16x8 fJ6  = cat44(pk[0], r1); xb[1] = fJ6;  xb[9] = fJ6;
          bf16x8 fJ12 = cat44(pk[2], r2); xb[2] = fJ12;
        }
      }
    }
  }
}

extern "C" void kernel_launch(void* const* d_in, const int* in_sizes, int n_in,
                              void* d_out, int out_size, void* d_ws, size_t ws_size,
                              hipStream_t stream)
{
  const float* sparse = (const float*)d_in[0];
  const float* dec    = (const float*)d_in[1];
  Biases bp;
  const float* w0[3]; const float* w1[3]; const float* w2[3]; const float* b0[3];
  for (int m = 0; m < 3; ++m) {
    w0[m]    = (const float*)d_in[2 + m * 6 + 0];
    b0[m]    = (const float*)d_in[2 + m * 6 + 1];
    w1[m]    = (const float*)d_in[2 + m * 6 + 2];
    bp.b1[m] = (const float*)d_in[2 + m * 6 + 3];
    w2[m]    = (const float*)d_in[2 + m * 6 + 4];
    bp.b2[m] = (const float*)d_in[2 + m * 6 + 5];
  }
  __bf16* ws = (__bf16*)d_ws;
  const int nrows = in_sizes[0] / DSP;   // 131072 = 512 * 256

  const int prep_total = 3 * MLP_WS;
  prep_weights<<<(prep_total + 255) / 256, 256, 0, stream>>>(
      w0[0], w1[0], w2[0], w0[1], w1[1], w2[1], w0[2], w1[2], w2[2],
      b0[0], b0[1], b0[2], ws);

  const int nblocks = nrows / BM;
  trunk_fused<<<nblocks, NTHR, 0, stream>>>(sparse, dec, ws, (float*)d_out, bp);
}